// Round 13
// baseline (1021.961 us; speedup 1.0000x reference)
//
#include <hip/hip_runtime.h>
#include <hip/hip_bf16.h>

// Problem constants (from reference)
#define FEAT 64          // IN_F = HID_F = OUT_F
#define CAT_F 128        // HID_F + IN_F
#define CAP   64         // ELL capacity; deg ~ Poisson(10), P(deg>64) ~ 0

// bf16 helpers
__device__ inline float blo(unsigned u) { union { unsigned x; float f; } v; v.x = u << 16; return v.f; }
__device__ inline unsigned short f2b(float f) {
    union { float f; unsigned u; } v; v.f = f;
    unsigned r = v.u + 0x7FFFu + ((v.u >> 16) & 1u);
    return (unsigned short)(r >> 16);
}

// ---------------------------------------------------------------------------
__global__ void detect_kernel(const unsigned int* ei, int* mode) {
    *mode = (ei[1] == 0u && ei[3] == 0u && ei[5] == 0u && ei[7] == 0u) ? 1 : 0;
}

// batch convert + root boundaries (batch is sorted; every graph non-empty)
__global__ void batch_prep(const void* __restrict__ bt, const int* __restrict__ mode,
                           int* __restrict__ batch32, int* __restrict__ root_idx,
                           int N, int G) {
    int i = blockIdx.x * blockDim.x + threadIdx.x;
    if (i >= N) return;
    int m = *mode;
    int b = m ? (int)((const long long*)bt)[i] : ((const int*)bt)[i];
    batch32[i] = b;
    if (i == 0) { root_idx[0] = 0; root_idx[G] = N; }
    else {
        int bp = m ? (int)((const long long*)bt)[i - 1] : ((const int*)bt)[i - 1];
        if (b != bp) root_idx[b] = i;
    }
}

// ---------------------------------------------------------------------------
// MEGA: [ell blocks | gemm1 blocks (inlined, k-split, unscaled out) | rootc]
// LDS cut to 24.7 KB (AsT[32][68]+Bs[64][64]) so ell blocks keep ~6 blocks/CU
// occupancy (round-12 lesson: 33.8 KB LDS -> 4 blocks/CU starved the
// atomic-latency-bound ell branch). gemm is textually inlined (round-7/8
// lesson: __device__ body with __shared__ pointer args spilled to scratch).
// Named float4 locals only (round-3 lesson).
__global__ __launch_bounds__(256, 4)
void mega(const void* __restrict__ ei, const int* __restrict__ mode,
          int* __restrict__ deg_cnt, int* __restrict__ cnt_col,
          int* __restrict__ ell, int E,
          const float* __restrict__ x, const float* __restrict__ w1,
          unsigned short* __restrict__ hs,
          const float* __restrict__ w2hi, const int* __restrict__ root_idx,
          float* __restrict__ rootc, int N, int G, int eb, int gb) {
    __shared__ float AsT[32][68];   // [k][row], half-K staging
    __shared__ float Bs[64][64];    // [k][col]
    int bid = blockIdx.x;

    if (bid < eb) {
        // ---- ELL build: per edge (r,c), r!=c: deg_cnt[r]++, slot=cnt_col[c]++,
        //      ell[c][slot]=r. Native edge dtype (wave-uniform branch).
        int e = bid * 256 + threadIdx.x;
        if (e < E) {
            int r, c;
            if (*mode) {
                const long long* p = (const long long*)ei;
                r = (int)p[e]; c = (int)p[E + e];
            } else {
                const int* p = (const int*)ei;
                r = p[e]; c = p[E + e];
            }
            if (r != c) {
                atomicAdd(&deg_cnt[r], 1);
                int slot = atomicAdd(&cnt_col[c], 1);
                if (slot < CAP) ell[c * CAP + slot] = r;
            }
        }
        return;
    }

    if (bid < eb + gb) {
        // ---- gemm1: hs[row] = bf16( x[row] @ w1 )   (UNSCALED; dis folded into agg1)
        const int tid = threadIdx.x;
        const long base = (long)(bid - eb) * 64;
#pragma unroll
        for (int u = 0; u < 4; ++u) {         // stage B fully (64x64)
            int v = tid + u * 256, row = v >> 4, c4 = (v & 15) * 4;
            *(float4*)&Bs[row][c4] = *(const float4*)&w1[row * 64 + c4];
        }
        const int c0 = (tid & 15) * 4;
        const int r0 = (tid >> 4) * 4;
        float4 acc0 = make_float4(0.f, 0.f, 0.f, 0.f);
        float4 acc1 = acc0, acc2 = acc0, acc3 = acc0;

#pragma unroll
        for (int h = 0; h < 2; ++h) {         // two 32-k halves
            __syncthreads();
#pragma unroll
            for (int u = 0; u < 2; ++u) {     // stage A half transposed
                int v = tid + u * 256, row = v >> 3, c4 = (v & 7) * 4;
                float4 av = make_float4(0.f, 0.f, 0.f, 0.f);
                if (base + row < N) av = *(const float4*)&x[(base + row) * 64 + h * 32 + c4];
                AsT[c4 + 0][row] = av.x;
                AsT[c4 + 1][row] = av.y;
                AsT[c4 + 2][row] = av.z;
                AsT[c4 + 3][row] = av.w;
            }
            __syncthreads();
#pragma unroll
            for (int kk = 0; kk < 32; ++kk) {
                float4 bv = *(const float4*)&Bs[h * 32 + kk][c0];
                float4 av = *(const float4*)&AsT[kk][r0];
                acc0.x = fmaf(av.x, bv.x, acc0.x); acc0.y = fmaf(av.x, bv.y, acc0.y);
                acc0.z = fmaf(av.x, bv.z, acc0.z); acc0.w = fmaf(av.x, bv.w, acc0.w);
                acc1.x = fmaf(av.y, bv.x, acc1.x); acc1.y = fmaf(av.y, bv.y, acc1.y);
                acc1.z = fmaf(av.y, bv.z, acc1.z); acc1.w = fmaf(av.y, bv.w, acc1.w);
                acc2.x = fmaf(av.z, bv.x, acc2.x); acc2.y = fmaf(av.z, bv.y, acc2.y);
                acc2.z = fmaf(av.z, bv.z, acc2.z); acc2.w = fmaf(av.z, bv.w, acc2.w);
                acc3.x = fmaf(av.w, bv.x, acc3.x); acc3.y = fmaf(av.w, bv.y, acc3.y);
                acc3.z = fmaf(av.w, bv.z, acc3.z); acc3.w = fmaf(av.w, bv.w, acc3.w);
            }
        }
#define STORE_ROW(i, a)                                                       \
        {                                                                     \
            long row = base + r0 + (i);                                       \
            if (row < N) {                                                    \
                ushort4 o;                                                    \
                o.x = f2b(a.x); o.y = f2b(a.y);                               \
                o.z = f2b(a.z); o.w = f2b(a.w);                               \
                *(ushort4*)&hs[row * 64 + c0] = o;                            \
            }                                                                 \
        }
        STORE_ROW(0, acc0)
        STORE_ROW(1, acc1)
        STORE_ROW(2, acc2)
        STORE_ROW(3, acc3)
#undef STORE_ROW
        return;
    }

    // ---- rootc: rootc[g] = relu(x[root_g]) @ w2[64:128]
    int g = ((bid - eb - gb) * 256 + threadIdx.x) >> 6;
    int f = threadIdx.x & 63;
    if (g >= G) return;
    const float* xr = x + (long)root_idx[g] * 64;
    float acc = 0.f;
#pragma unroll
    for (int k = 0; k < 64; ++k)
        acc = fmaf(fmaxf(xr[k], 0.f), w2hi[k * 64 + f], acc);
    rootc[(long)g * 64 + f] = acc;
}

// dis = (1+deg)^-1/2 (tiny; runs right after mega)
__global__ void dis_kernel(const int* __restrict__ deg_cnt, float* __restrict__ dis, int N) {
    int i = blockIdx.x * blockDim.x + threadIdx.x;
    if (i >= N) return;
    dis[i] = rsqrtf(1.0f + (float)deg_cnt[i]);
}

// ---------------------------------------------------------------------------
// Register-tiled GEMM (monolithic, proven): conv2 transform
//   hs[row][f] = bf16( dis[row] * (relu(A[row]) @ B + rootc[batch[row]]) )
__global__ __launch_bounds__(256, 4)
void gemm2_kernel(const float* __restrict__ A, const float* __restrict__ B,
                  const float* __restrict__ addv, const int* __restrict__ batch32,
                  const float* __restrict__ dis, unsigned short* __restrict__ hs, int N) {
    __shared__ float AsT[64][68];   // [k][row]
    __shared__ float Bs[64][64];    // [k][col]
    const int tid = threadIdx.x;
    const long base = (long)blockIdx.x * 64;

#pragma unroll
    for (int u = 0; u < 4; ++u) {
        int v   = tid + u * 256;
        int row = v >> 4;
        int c4  = (v & 15) * 4;
        float4 bv = *(const float4*)&B[row * 64 + c4];
        *(float4*)&Bs[row][c4] = bv;
        float4 av = make_float4(0.f, 0.f, 0.f, 0.f);
        if (base + row < N) av = *(const float4*)&A[(base + row) * 64 + c4];
        av.x = fmaxf(av.x, 0.f); av.y = fmaxf(av.y, 0.f);
        av.z = fmaxf(av.z, 0.f); av.w = fmaxf(av.w, 0.f);
        AsT[c4 + 0][row] = av.x;
        AsT[c4 + 1][row] = av.y;
        AsT[c4 + 2][row] = av.z;
        AsT[c4 + 3][row] = av.w;
    }
    __syncthreads();

    const int c0 = (tid & 15) * 4;
    const int r0 = (tid >> 4) * 4;
    float4 acc0 = make_float4(0.f, 0.f, 0.f, 0.f);
    float4 acc1 = acc0, acc2 = acc0, acc3 = acc0;

#pragma unroll 4
    for (int k = 0; k < 64; ++k) {
        float4 bv = *(const float4*)&Bs[k][c0];
        float4 av = *(const float4*)&AsT[k][r0];
        acc0.x = fmaf(av.x, bv.x, acc0.x); acc0.y = fmaf(av.x, bv.y, acc0.y);
        acc0.z = fmaf(av.x, bv.z, acc0.z); acc0.w = fmaf(av.x, bv.w, acc0.w);
        acc1.x = fmaf(av.y, bv.x, acc1.x); acc1.y = fmaf(av.y, bv.y, acc1.y);
        acc1.z = fmaf(av.y, bv.z, acc1.z); acc1.w = fmaf(av.y, bv.w, acc1.w);
        acc2.x = fmaf(av.z, bv.x, acc2.x); acc2.y = fmaf(av.z, bv.y, acc2.y);
        acc2.z = fmaf(av.z, bv.z, acc2.z); acc2.w = fmaf(av.z, bv.w, acc2.w);
        acc3.x = fmaf(av.w, bv.x, acc3.x); acc3.y = fmaf(av.w, bv.y, acc3.y);
        acc3.z = fmaf(av.w, bv.z, acc3.z); acc3.w = fmaf(av.w, bv.w, acc3.w);
    }

#define STORE_ROW(i, a)                                                       \
    {                                                                         \
        long row = base + r0 + (i);                                           \
        if (row < N) {                                                        \
            int g = batch32[row];                                             \
            float4 adv = *(const float4*)&addv[(long)g * 64 + c0];            \
            a.x += adv.x; a.y += adv.y; a.z += adv.z; a.w += adv.w;           \
            float s = dis[row];                                               \
            ushort4 o;                                                        \
            o.x = f2b(s * a.x); o.y = f2b(s * a.y);                           \
            o.z = f2b(s * a.z); o.w = f2b(s * a.w);                           \
            *(ushort4*)&hs[row * 64 + c0] = o;                                \
        }                                                                     \
    }
    STORE_ROW(0, acc0)
    STORE_ROW(1, acc1)
    STORE_ROW(2, acc2)
    STORE_ROW(3, acc3)
#undef STORE_ROW
}

// ---------------------------------------------------------------------------
// gather_sum: acc[f] = Sum_e hs[row_e][f]          (prescaled rows, conv2)
// gather_sum_scaled: acc[f] = Sum_e dis[row_e]*hs[row_e][f]  (raw rows, conv1)
// lane = feature; edge ids pre-loaded (one coalesced read) + __shfl broadcast;
// dis[r] loads are wave-uniform -> one L2 sector per edge.
__device__ inline float gather_sum(const unsigned short* __restrict__ hs,
                                   const int* __restrict__ row, int cnt, int lane) {
    int rv = (lane < cnt) ? row[lane] : 0;
    float acc = 0.f;
    int j = 0;
    for (; j + 4 <= cnt; j += 4) {
        int r0 = __shfl(rv, j,     64);
        int r1 = __shfl(rv, j + 1, 64);
        int r2 = __shfl(rv, j + 2, 64);
        int r3 = __shfl(rv, j + 3, 64);
        float v0 = blo(hs[r0 * 64 + lane]);
        float v1 = blo(hs[r1 * 64 + lane]);
        float v2 = blo(hs[r2 * 64 + lane]);
        float v3 = blo(hs[r3 * 64 + lane]);
        acc += v0; acc += v1; acc += v2; acc += v3;
    }
    for (; j < cnt; ++j) {
        int r = __shfl(rv, j, 64);
        acc += blo(hs[r * 64 + lane]);
    }
    return acc;
}

__device__ inline float gather_sum_scaled(const unsigned short* __restrict__ hs,
                                          const float* __restrict__ dis,
                                          const int* __restrict__ row, int cnt, int lane) {
    int rv = (lane < cnt) ? row[lane] : 0;
    float acc = 0.f;
    int j = 0;
    for (; j + 4 <= cnt; j += 4) {
        int r0 = __shfl(rv, j,     64);
        int r1 = __shfl(rv, j + 1, 64);
        int r2 = __shfl(rv, j + 2, 64);
        int r3 = __shfl(rv, j + 3, 64);
        float d0 = dis[r0], d1 = dis[r1], d2 = dis[r2], d3 = dis[r3];
        float v0 = blo(hs[r0 * 64 + lane]);
        float v1 = blo(hs[r1 * 64 + lane]);
        float v2 = blo(hs[r2 * 64 + lane]);
        float v3 = blo(hs[r3 * 64 + lane]);
        acc = fmaf(d0, v0, acc);
        acc = fmaf(d1, v1, acc);
        acc = fmaf(d2, v2, acc);
        acc = fmaf(d3, v3, acc);
    }
    for (; j < cnt; ++j) {
        int r = __shfl(rv, j, 64);
        acc = fmaf(dis[r], blo(hs[r * 64 + lane]), acc);
    }
    return acc;
}

// conv1 aggregation on RAW hs (dis folded in per edge):
//   x2[node][f] = dis[node]*(Sum_e dis[r]*hs[r][f] + dis[node]*hs[node][f]) + b1[f]
__global__ void agg1_kernel(const unsigned short* __restrict__ hs, const float* __restrict__ dis,
                            const int* __restrict__ cnt_col, const int* __restrict__ ell,
                            const float* __restrict__ bias, float* __restrict__ x2, int N) {
    int node = (blockIdx.x * blockDim.x + threadIdx.x) >> 6;
    int lane = threadIdx.x & 63;
    if (node >= N) return;
    int cnt = min(cnt_col[node], CAP);
    float acc = gather_sum_scaled(hs, dis, ell + (long)node * CAP, cnt, lane);
    float dc = dis[node];
    float self = blo(hs[node * 64 + lane]);
    // x2 = dc*(acc + dc*self) + b
    x2[(long)node * 64 + lane] = fmaf(dc, fmaf(dc, self, acc), bias[lane]);
}

// conv2 aggregation partials: graph g split into 4 chunks; block (4 waves)
// per chunk accumulates Sum_n relu(dis[n]*(Sum_e + self) + b2) over its nodes.
__global__ __launch_bounds__(256)
void agg2_part(const unsigned short* __restrict__ hs, const float* __restrict__ dis,
               const int* __restrict__ cnt_col, const int* __restrict__ ell,
               const float* __restrict__ bias, const int* __restrict__ root_idx,
               float* __restrict__ partial) {
    __shared__ float ls[4][64];
    int g  = blockIdx.x >> 2;
    int ch = blockIdx.x & 3;
    int root = root_idx[g], nend = root_idx[g + 1];
    int len = nend - root;
    int chunk = (len + 3) >> 2;
    int start = root + ch * chunk;
    int end   = min(start + chunk, nend);
    int wid  = threadIdx.x >> 6;
    int lane = threadIdx.x & 63;
    float bv = bias[lane];
    float s = 0.f;
    for (int node = start + wid; node < end; node += 4) {
        int cnt = min(cnt_col[node], CAP);
        float acc = gather_sum(hs, ell + (long)node * CAP, cnt, lane);
        float dc = dis[node];
        float self = blo(hs[node * 64 + lane]);
        s += fmaxf(fmaf(dc, acc + self, bv), 0.f);
    }
    ls[wid][lane] = s;
    __syncthreads();
    if (threadIdx.x < 64) {
        float v = ls[0][threadIdx.x] + ls[1][threadIdx.x] +
                  ls[2][threadIdx.x] + ls[3][threadIdx.x];
        partial[(long)blockIdx.x * 64 + threadIdx.x] = v;
    }
}

// final: out[g][0:64] = (Sum of 4 chunk partials)/len ; out[g][64:128] = x2[root]
__global__ void final_reduce(const float* __restrict__ partial, const int* __restrict__ root_idx,
                             const float* __restrict__ x2, float* __restrict__ out) {
    int g = blockIdx.x;
    int f = threadIdx.x;    // 64
    int root = root_idx[g];
    int len  = root_idx[g + 1] - root;
    const float* p = partial + (long)g * 4 * 64;
    float v = p[f] + p[64 + f] + p[128 + f] + p[192 + f];
    out[(long)g * CAT_F + f] = v / (float)len;
    out[(long)g * CAT_F + 64 + f] = x2[(long)root * 64 + f];
}

// ---------------------------------------------------------------------------
extern "C" void kernel_launch(void* const* d_in, const int* in_sizes, int n_in,
                              void* d_out, int out_size, void* d_ws, size_t ws_size,
                              hipStream_t stream) {
    const float* x  = (const float*)d_in[0];
    const void*  ei = d_in[1];
    const void*  bt = d_in[2];
    const float* w1 = (const float*)d_in[3];
    const float* b1 = (const float*)d_in[4];
    const float* w2 = (const float*)d_in[5];
    const float* b2 = (const float*)d_in[6];
    float* out = (float*)d_out;

    const int N = in_sizes[0] / FEAT;     // 100000
    const int E = in_sizes[1] / 2;        // 1000000
    const int G = out_size / CAT_F;       // 500

    // workspace layout
    char* p = (char*)d_ws;
    size_t off = 0;
    auto alloc = [&](size_t bytes) {
        void* q = p + off;
        off = (off + bytes + 255) & ~(size_t)255;
        return q;
    };
    int*   mode     = (int*)  alloc(sizeof(int));
    int*   batch32  = (int*)  alloc((size_t)N * sizeof(int));
    int*   deg_cnt  = (int*)  alloc((size_t)N * sizeof(int));
    float* dis      = (float*)alloc((size_t)N * sizeof(float));
    int*   cnt_col  = (int*)  alloc((size_t)N * sizeof(int));
    int*   ell      = (int*)  alloc((size_t)N * CAP * sizeof(int));
    int*   root_idx = (int*)  alloc((size_t)(G + 1) * sizeof(int));
    float* rootc    = (float*)alloc((size_t)G * FEAT * sizeof(float));
    unsigned short* hs = (unsigned short*)alloc((size_t)N * FEAT * sizeof(unsigned short));
    float* x2       = (float*)alloc((size_t)N * FEAT * sizeof(float));
    float* partial  = (float*)alloc((size_t)G * 4 * FEAT * sizeof(float));
    (void)ws_size; (void)n_in;

    hipMemsetAsync(deg_cnt, 0, (size_t)N * sizeof(int), stream);
    hipMemsetAsync(cnt_col, 0, (size_t)N * sizeof(int), stream);

    detect_kernel<<<1, 1, 0, stream>>>((const unsigned int*)ei, mode);
    batch_prep<<<(N + 255) / 256, 256, 0, stream>>>(bt, mode, batch32, root_idx, N, G);

    // fused [ell | gemm1(unscaled, k-split LDS) | rootc]
    const int eb = (E + 255) / 256;
    const int gb = (N + 63) / 64;
    const int rb = (G * FEAT + 255) / 256;
    mega<<<eb + gb + rb, 256, 0, stream>>>(ei, mode, deg_cnt, cnt_col, ell, E,
                                           x, w1, hs, w2 + FEAT * FEAT, root_idx,
                                           rootc, N, G, eb, gb);

    // dis only (prescale eliminated — dis folded into agg1 per edge)
    dis_kernel<<<(N + 255) / 256, 256, 0, stream>>>(deg_cnt, dis, N);

    const int agg_blocks = (N + 3) / 4;

    // conv1 aggregation on raw hs: x2 = dis*(Sum dis[r]*hs[r] + dis*hs[self]) + b1
    agg1_kernel<<<agg_blocks, 256, 0, stream>>>(hs, dis, cnt_col, ell, b1, x2, N);

    // conv2 transform: hs = bf16(dis * (relu(x2) @ w2lo + rootc[batch]))
    gemm2_kernel<<<gb, 256, 0, stream>>>(x2, w2, rootc, batch32, dis, hs, N);

    // conv2 aggregation partials (4 chunks per graph) + deterministic reduce
    agg2_part<<<G * 4, 256, 0, stream>>>(hs, dis, cnt_col, ell, b2, root_idx, partial);
    final_reduce<<<G, 64, 0, stream>>>(partial, root_idx, x2, out);
}

// Round 14
// 245.628 us; speedup vs baseline: 4.1606x; 4.1606x over previous
//
#include <hip/hip_runtime.h>
#include <hip/hip_bf16.h>

// Problem constants (from reference)
#define FEAT 64          // IN_F = HID_F = OUT_F
#define CAT_F 128        // HID_F + IN_F
#define CAP   64         // ELL capacity; deg ~ Poisson(10), P(deg>64) ~ 0

// bf16 helpers
__device__ inline float blo(unsigned u) { union { unsigned x; float f; } v; v.x = u << 16; return v.f; }
__device__ inline unsigned short f2b(float f) {
    union { float f; unsigned u; } v; v.f = f;
    unsigned r = v.u + 0x7FFFu + ((v.u >> 16) & 1u);
    return (unsigned short)(r >> 16);
}

// ---------------------------------------------------------------------------
__global__ void detect_kernel(const unsigned int* ei, int* mode) {
    *mode = (ei[1] == 0u && ei[3] == 0u && ei[5] == 0u && ei[7] == 0u) ? 1 : 0;
}

// batch convert + root boundaries (batch is sorted; every graph non-empty)
__global__ void batch_prep(const void* __restrict__ bt, const int* __restrict__ mode,
                           int* __restrict__ batch32, int* __restrict__ root_idx,
                           int N, int G) {
    int i = blockIdx.x * blockDim.x + threadIdx.x;
    if (i >= N) return;
    int m = *mode;
    int b = m ? (int)((const long long*)bt)[i] : ((const int*)bt)[i];
    batch32[i] = b;
    if (i == 0) { root_idx[0] = 0; root_idx[G] = N; }
    else {
        int bp = m ? (int)((const long long*)bt)[i - 1] : ((const int*)bt)[i - 1];
        if (b != bp) root_idx[b] = i;
    }
}

// ---------------------------------------------------------------------------
// MEGA: [ell blocks | gemm1 blocks | rootc blocks]
// gemm1 uses Bs-ONLY LDS (16.4 KB) and reads A directly from global (L1-hot
// 16 KB tile) -> up to 8 blocks/CU so the atomic-latency-bound ell branch
// keeps full occupancy (round-12 lesson: 33.8 KB LDS -> 4 blocks/CU, -26 us).
// NO k-split: accumulators must not live across a __syncthreads inside a
// loop (round-13 lesson: that re-triggers the 64-VGPR spill, 1.5 GB scratch).
// gemm inlined (round-7/8), named float4 locals only (round-3).
__global__ __launch_bounds__(256, 4)
void mega(const void* __restrict__ ei, const int* __restrict__ mode,
          int* __restrict__ deg_cnt, int* __restrict__ cnt_col,
          int* __restrict__ ell, int E,
          const float* __restrict__ x, const float* __restrict__ w1,
          unsigned short* __restrict__ hs,
          const float* __restrict__ w2hi, const int* __restrict__ root_idx,
          float* __restrict__ rootc, int N, int G, int eb, int gb) {
    __shared__ float Bs[64][64];    // [k][col] — the only LDS
    int bid = blockIdx.x;

    if (bid < eb) {
        // ---- ELL build: per edge (r,c), r!=c: deg_cnt[r]++, slot=cnt_col[c]++,
        //      ell[c][slot]=r. Native edge dtype (wave-uniform branch).
        int e = bid * 256 + threadIdx.x;
        if (e < E) {
            int r, c;
            if (*mode) {
                const long long* p = (const long long*)ei;
                r = (int)p[e]; c = (int)p[E + e];
            } else {
                const int* p = (const int*)ei;
                r = p[e]; c = p[E + e];
            }
            if (r != c) {
                atomicAdd(&deg_cnt[r], 1);
                int slot = atomicAdd(&cnt_col[c], 1);
                if (slot < CAP) ell[c * CAP + slot] = r;
            }
        }
        return;
    }

    if (bid < eb + gb) {
        // ---- gemm1: hs[row] = bf16( x[row] @ w1 )  (UNSCALED; dis folded in agg1)
        const int tid = threadIdx.x;
        const long base = (long)(bid - eb) * 64;
#pragma unroll
        for (int u = 0; u < 4; ++u) {          // stage B (64x64 fp32)
            int v = tid + u * 256, row = v >> 4, c4 = (v & 15) * 4;
            *(float4*)&Bs[row][c4] = *(const float4*)&w1[row * 64 + c4];
        }
        __syncthreads();

        const int c0 = (tid & 15) * 4;
        const int r0 = (tid >> 4) * 4;
        long rA = base + r0;
        long rc0 = rA + 0 < N ? rA + 0 : N - 1;
        long rc1 = rA + 1 < N ? rA + 1 : N - 1;
        long rc2 = rA + 2 < N ? rA + 2 : N - 1;
        long rc3 = rA + 3 < N ? rA + 3 : N - 1;
        const float* A0 = x + rc0 * 64;
        const float* A1 = x + rc1 * 64;
        const float* A2 = x + rc2 * 64;
        const float* A3 = x + rc3 * 64;

        float4 acc0 = make_float4(0.f, 0.f, 0.f, 0.f);
        float4 acc1 = acc0, acc2 = acc0, acc3 = acc0;
#pragma unroll 4
        for (int k = 0; k < 64; ++k) {
            float4 bv = *(const float4*)&Bs[k][c0];
            float a0 = A0[k], a1 = A1[k], a2 = A2[k], a3 = A3[k];
            acc0.x = fmaf(a0, bv.x, acc0.x); acc0.y = fmaf(a0, bv.y, acc0.y);
            acc0.z = fmaf(a0, bv.z, acc0.z); acc0.w = fmaf(a0, bv.w, acc0.w);
            acc1.x = fmaf(a1, bv.x, acc1.x); acc1.y = fmaf(a1, bv.y, acc1.y);
            acc1.z = fmaf(a1, bv.z, acc1.z); acc1.w = fmaf(a1, bv.w, acc1.w);
            acc2.x = fmaf(a2, bv.x, acc2.x); acc2.y = fmaf(a2, bv.y, acc2.y);
            acc2.z = fmaf(a2, bv.z, acc2.z); acc2.w = fmaf(a2, bv.w, acc2.w);
            acc3.x = fmaf(a3, bv.x, acc3.x); acc3.y = fmaf(a3, bv.y, acc3.y);
            acc3.z = fmaf(a3, bv.z, acc3.z); acc3.w = fmaf(a3, bv.w, acc3.w);
        }
#define STORE_ROW(i, a)                                                       \
        {                                                                     \
            long row = base + r0 + (i);                                       \
            if (row < N) {                                                    \
                ushort4 o;                                                    \
                o.x = f2b(a.x); o.y = f2b(a.y);                               \
                o.z = f2b(a.z); o.w = f2b(a.w);                               \
                *(ushort4*)&hs[row * 64 + c0] = o;                            \
            }                                                                 \
        }
        STORE_ROW(0, acc0)
        STORE_ROW(1, acc1)
        STORE_ROW(2, acc2)
        STORE_ROW(3, acc3)
#undef STORE_ROW
        return;
    }

    // ---- rootc: rootc[g] = relu(x[root_g]) @ w2[64:128]
    int g = ((bid - eb - gb) * 256 + threadIdx.x) >> 6;
    int f = threadIdx.x & 63;
    if (g >= G) return;
    const float* xr = x + (long)root_idx[g] * 64;
    float acc = 0.f;
#pragma unroll
    for (int k = 0; k < 64; ++k)
        acc = fmaf(fmaxf(xr[k], 0.f), w2hi[k * 64 + f], acc);
    rootc[(long)g * 64 + f] = acc;
}

// dis = (1+deg)^-1/2
__global__ void dis_kernel(const int* __restrict__ deg_cnt, float* __restrict__ dis, int N) {
    int i = blockIdx.x * blockDim.x + threadIdx.x;
    if (i >= N) return;
    dis[i] = rsqrtf(1.0f + (float)deg_cnt[i]);
}

// ---------------------------------------------------------------------------
// gather_sum: acc[f] = Sum_e hs[row_e][f]          (prescaled rows, conv2)
// gather_sum_scaled: acc[f] = Sum_e dis[row_e]*hs[row_e][f]  (raw rows, conv1)
__device__ inline float gather_sum(const unsigned short* __restrict__ hs,
                                   const int* __restrict__ row, int cnt, int lane) {
    int rv = (lane < cnt) ? row[lane] : 0;
    float acc = 0.f;
    int j = 0;
    for (; j + 4 <= cnt; j += 4) {
        int r0 = __shfl(rv, j,     64);
        int r1 = __shfl(rv, j + 1, 64);
        int r2 = __shfl(rv, j + 2, 64);
        int r3 = __shfl(rv, j + 3, 64);
        float v0 = blo(hs[r0 * 64 + lane]);
        float v1 = blo(hs[r1 * 64 + lane]);
        float v2 = blo(hs[r2 * 64 + lane]);
        float v3 = blo(hs[r3 * 64 + lane]);
        acc += v0; acc += v1; acc += v2; acc += v3;
    }
    for (; j < cnt; ++j) {
        int r = __shfl(rv, j, 64);
        acc += blo(hs[r * 64 + lane]);
    }
    return acc;
}

__device__ inline float gather_sum_scaled(const unsigned short* __restrict__ hs,
                                          const float* __restrict__ dis,
                                          const int* __restrict__ row, int cnt, int lane) {
    int rv = (lane < cnt) ? row[lane] : 0;
    float acc = 0.f;
    int j = 0;
    for (; j + 4 <= cnt; j += 4) {
        int r0 = __shfl(rv, j,     64);
        int r1 = __shfl(rv, j + 1, 64);
        int r2 = __shfl(rv, j + 2, 64);
        int r3 = __shfl(rv, j + 3, 64);
        float d0 = dis[r0], d1 = dis[r1], d2 = dis[r2], d3 = dis[r3];
        float v0 = blo(hs[r0 * 64 + lane]);
        float v1 = blo(hs[r1 * 64 + lane]);
        float v2 = blo(hs[r2 * 64 + lane]);
        float v3 = blo(hs[r3 * 64 + lane]);
        acc = fmaf(d0, v0, acc);
        acc = fmaf(d1, v1, acc);
        acc = fmaf(d2, v2, acc);
        acc = fmaf(d3, v3, acc);
    }
    for (; j < cnt; ++j) {
        int r = __shfl(rv, j, 64);
        acc = fmaf(dis[r], blo(hs[r * 64 + lane]), acc);
    }
    return acc;
}

// conv1 aggregation on RAW hs (dis folded in per edge), bf16 output:
//   x2b[node][f] = bf16( dis[node]*(Sum_e dis[r]*hs[r][f] + dis[node]*hs[node][f]) + b1[f] )
__global__ void agg1_kernel(const unsigned short* __restrict__ hs, const float* __restrict__ dis,
                            const int* __restrict__ cnt_col, const int* __restrict__ ell,
                            const float* __restrict__ bias, unsigned short* __restrict__ x2b,
                            int N) {
    int node = (blockIdx.x * blockDim.x + threadIdx.x) >> 6;
    int lane = threadIdx.x & 63;
    if (node >= N) return;
    int cnt = min(cnt_col[node], CAP);
    float acc = gather_sum_scaled(hs, dis, ell + (long)node * CAP, cnt, lane);
    float dc = dis[node];
    float self = blo(hs[node * 64 + lane]);
    float v = fmaf(dc, fmaf(dc, self, acc), bias[lane]);
    x2b[(long)node * 64 + lane] = f2b(v);
}

// ---------------------------------------------------------------------------
// gemm2: hs[row][f] = bf16( dis[row] * (relu(x2b[row]) @ B + rootc[batch[row]]) )
// A input is bf16 (x2b); staged with relu into fp32 LDS.
__global__ __launch_bounds__(256, 4)
void gemm2_kernel(const unsigned short* __restrict__ x2b, const float* __restrict__ B,
                  const float* __restrict__ addv, const int* __restrict__ batch32,
                  const float* __restrict__ dis, unsigned short* __restrict__ hs, int N) {
    __shared__ float AsT[64][68];   // [k][row]
    __shared__ float Bs[64][64];    // [k][col]
    const int tid = threadIdx.x;
    const long base = (long)blockIdx.x * 64;

#pragma unroll
    for (int u = 0; u < 4; ++u) {
        int v   = tid + u * 256;
        int row = v >> 4;
        int c4  = (v & 15) * 4;
        float4 bv = *(const float4*)&B[row * 64 + c4];
        *(float4*)&Bs[row][c4] = bv;
        float a0 = 0.f, a1 = 0.f, a2 = 0.f, a3 = 0.f;
        if (base + row < N) {
            ushort4 o = *(const ushort4*)&x2b[(base + row) * 64 + c4];
            a0 = blo(o.x); a1 = blo(o.y); a2 = blo(o.z); a3 = blo(o.w);
        }
        AsT[c4 + 0][row] = fmaxf(a0, 0.f);
        AsT[c4 + 1][row] = fmaxf(a1, 0.f);
        AsT[c4 + 2][row] = fmaxf(a2, 0.f);
        AsT[c4 + 3][row] = fmaxf(a3, 0.f);
    }
    __syncthreads();

    const int c0 = (tid & 15) * 4;
    const int r0 = (tid >> 4) * 4;
    float4 acc0 = make_float4(0.f, 0.f, 0.f, 0.f);
    float4 acc1 = acc0, acc2 = acc0, acc3 = acc0;

#pragma unroll 4
    for (int k = 0; k < 64; ++k) {
        float4 bv = *(const float4*)&Bs[k][c0];
        float4 av = *(const float4*)&AsT[k][r0];
        acc0.x = fmaf(av.x, bv.x, acc0.x); acc0.y = fmaf(av.x, bv.y, acc0.y);
        acc0.z = fmaf(av.x, bv.z, acc0.z); acc0.w = fmaf(av.x, bv.w, acc0.w);
        acc1.x = fmaf(av.y, bv.x, acc1.x); acc1.y = fmaf(av.y, bv.y, acc1.y);
        acc1.z = fmaf(av.y, bv.z, acc1.z); acc1.w = fmaf(av.y, bv.w, acc1.w);
        acc2.x = fmaf(av.z, bv.x, acc2.x); acc2.y = fmaf(av.z, bv.y, acc2.y);
        acc2.z = fmaf(av.z, bv.z, acc2.z); acc2.w = fmaf(av.z, bv.w, acc2.w);
        acc3.x = fmaf(av.w, bv.x, acc3.x); acc3.y = fmaf(av.w, bv.y, acc3.y);
        acc3.z = fmaf(av.w, bv.z, acc3.z); acc3.w = fmaf(av.w, bv.w, acc3.w);
    }

#define STORE_ROW(i, a)                                                       \
    {                                                                         \
        long row = base + r0 + (i);                                           \
        if (row < N) {                                                        \
            int g = batch32[row];                                             \
            float4 adv = *(const float4*)&addv[(long)g * 64 + c0];            \
            a.x += adv.x; a.y += adv.y; a.z += adv.z; a.w += adv.w;           \
            float s = dis[row];                                               \
            ushort4 o;                                                        \
            o.x = f2b(s * a.x); o.y = f2b(s * a.y);                           \
            o.z = f2b(s * a.z); o.w = f2b(s * a.w);                           \
            *(ushort4*)&hs[row * 64 + c0] = o;                                \
        }                                                                     \
    }
    STORE_ROW(0, acc0)
    STORE_ROW(1, acc1)
    STORE_ROW(2, acc2)
    STORE_ROW(3, acc3)
#undef STORE_ROW
}

// conv2 aggregation partials: graph g split into 4 chunks; block (4 waves)
// per chunk accumulates Sum_n relu(dis[n]*(Sum_e + self) + b2) over its nodes.
__global__ __launch_bounds__(256)
void agg2_part(const unsigned short* __restrict__ hs, const float* __restrict__ dis,
               const int* __restrict__ cnt_col, const int* __restrict__ ell,
               const float* __restrict__ bias, const int* __restrict__ root_idx,
               float* __restrict__ partial) {
    __shared__ float ls[4][64];
    int g  = blockIdx.x >> 2;
    int ch = blockIdx.x & 3;
    int root = root_idx[g], nend = root_idx[g + 1];
    int len = nend - root;
    int chunk = (len + 3) >> 2;
    int start = root + ch * chunk;
    int end   = min(start + chunk, nend);
    int wid  = threadIdx.x >> 6;
    int lane = threadIdx.x & 63;
    float bv = bias[lane];
    float s = 0.f;
    for (int node = start + wid; node < end; node += 4) {
        int cnt = min(cnt_col[node], CAP);
        float acc = gather_sum(hs, ell + (long)node * CAP, cnt, lane);
        float dc = dis[node];
        float self = blo(hs[node * 64 + lane]);
        s += fmaxf(fmaf(dc, acc + self, bv), 0.f);
    }
    ls[wid][lane] = s;
    __syncthreads();
    if (threadIdx.x < 64) {
        float v = ls[0][threadIdx.x] + ls[1][threadIdx.x] +
                  ls[2][threadIdx.x] + ls[3][threadIdx.x];
        partial[(long)blockIdx.x * 64 + threadIdx.x] = v;
    }
}

// final: out[g][0:64] = (Sum of 4 chunk partials)/len ; out[g][64:128] = x2b[root]
__global__ void final_reduce(const float* __restrict__ partial, const int* __restrict__ root_idx,
                             const unsigned short* __restrict__ x2b, float* __restrict__ out) {
    int g = blockIdx.x;
    int f = threadIdx.x;    // 64
    int root = root_idx[g];
    int len  = root_idx[g + 1] - root;
    const float* p = partial + (long)g * 4 * 64;
    float v = p[f] + p[64 + f] + p[128 + f] + p[192 + f];
    out[(long)g * CAT_F + f] = v / (float)len;
    out[(long)g * CAT_F + 64 + f] = blo((unsigned)x2b[(long)root * 64 + f]);
}

// ---------------------------------------------------------------------------
extern "C" void kernel_launch(void* const* d_in, const int* in_sizes, int n_in,
                              void* d_out, int out_size, void* d_ws, size_t ws_size,
                              hipStream_t stream) {
    const float* x  = (const float*)d_in[0];
    const void*  ei = d_in[1];
    const void*  bt = d_in[2];
    const float* w1 = (const float*)d_in[3];
    const float* b1 = (const float*)d_in[4];
    const float* w2 = (const float*)d_in[5];
    const float* b2 = (const float*)d_in[6];
    float* out = (float*)d_out;

    const int N = in_sizes[0] / FEAT;     // 100000
    const int E = in_sizes[1] / 2;        // 1000000
    const int G = out_size / CAT_F;       // 500

    // workspace layout
    char* p = (char*)d_ws;
    size_t off = 0;
    auto alloc = [&](size_t bytes) {
        void* q = p + off;
        off = (off + bytes + 255) & ~(size_t)255;
        return q;
    };
    int*   mode     = (int*)  alloc(sizeof(int));
    int*   batch32  = (int*)  alloc((size_t)N * sizeof(int));
    int*   deg_cnt  = (int*)  alloc((size_t)N * sizeof(int));
    float* dis      = (float*)alloc((size_t)N * sizeof(float));
    int*   cnt_col  = (int*)  alloc((size_t)N * sizeof(int));
    int*   ell      = (int*)  alloc((size_t)N * CAP * sizeof(int));
    int*   root_idx = (int*)  alloc((size_t)(G + 1) * sizeof(int));
    float* rootc    = (float*)alloc((size_t)G * FEAT * sizeof(float));
    unsigned short* hs  = (unsigned short*)alloc((size_t)N * FEAT * sizeof(unsigned short));
    unsigned short* x2b = (unsigned short*)alloc((size_t)N * FEAT * sizeof(unsigned short));
    float* partial  = (float*)alloc((size_t)G * 4 * FEAT * sizeof(float));
    (void)ws_size; (void)n_in;

    hipMemsetAsync(deg_cnt, 0, (size_t)N * sizeof(int), stream);
    hipMemsetAsync(cnt_col, 0, (size_t)N * sizeof(int), stream);

    detect_kernel<<<1, 1, 0, stream>>>((const unsigned int*)ei, mode);
    batch_prep<<<(N + 255) / 256, 256, 0, stream>>>(bt, mode, batch32, root_idx, N, G);

    // fused [ell | gemm1(Bs-only LDS, A direct) | rootc]
    const int eb = (E + 255) / 256;
    const int gb = (N + 63) / 64;
    const int rb = (G * FEAT + 255) / 256;
    mega<<<eb + gb + rb, 256, 0, stream>>>(ei, mode, deg_cnt, cnt_col, ell, E,
                                           x, w1, hs, w2 + FEAT * FEAT, root_idx,
                                           rootc, N, G, eb, gb);

    dis_kernel<<<(N + 255) / 256, 256, 0, stream>>>(deg_cnt, dis, N);

    const int agg_blocks = (N + 3) / 4;

    // conv1 aggregation on raw hs (per-edge dis), bf16 x2 out
    agg1_kernel<<<agg_blocks, 256, 0, stream>>>(hs, dis, cnt_col, ell, b1, x2b, N);

    // conv2 transform: hs = bf16(dis * (relu(x2b) @ w2lo + rootc[batch]))
    gemm2_kernel<<<gb, 256, 0, stream>>>(x2b, w2, rootc, batch32, dis, hs, N);

    // conv2 aggregation partials (4 chunks per graph) + deterministic reduce
    agg2_part<<<G * 4, 256, 0, stream>>>(hs, dis, cnt_col, ell, b2, root_idx, partial);
    final_reduce<<<G, 64, 0, stream>>>(partial, root_idx, x2b, out);
}

// Round 15
// 234.627 us; speedup vs baseline: 4.3557x; 1.0469x over previous
//
#include <hip/hip_runtime.h>
#include <hip/hip_bf16.h>

// Problem constants (from reference)
#define FEAT 64          // IN_F = HID_F = OUT_F
#define CAT_F 128        // HID_F + IN_F
#define CAP   64         // ELL capacity; deg ~ Poisson(10), P(deg>64) ~ 0

// bf16 helpers: a uint holds 2 bf16 (low ushort = even feat, high = odd feat)
__device__ inline float blo(unsigned u) { union { unsigned x; float f; } v; v.x = u << 16; return v.f; }
__device__ inline float bhi(unsigned u) { union { unsigned x; float f; } v; v.x = u & 0xFFFF0000u; return v.f; }
__device__ inline unsigned short f2b(float f) {
    union { float f; unsigned u; } v; v.f = f;
    unsigned r = v.u + 0x7FFFu + ((v.u >> 16) & 1u);
    return (unsigned short)(r >> 16);
}
__device__ inline unsigned pk2(float lo, float hi) {
    return (unsigned)f2b(lo) | ((unsigned)f2b(hi) << 16);
}

// ---------------------------------------------------------------------------
__global__ void detect_kernel(const unsigned int* ei, int* mode) {
    *mode = (ei[1] == 0u && ei[3] == 0u && ei[5] == 0u && ei[7] == 0u) ? 1 : 0;
}

// batch convert + root boundaries (batch is sorted; every graph non-empty)
__global__ void batch_prep(const void* __restrict__ bt, const int* __restrict__ mode,
                           int* __restrict__ batch32, int* __restrict__ root_idx,
                           int N, int G) {
    int i = blockIdx.x * blockDim.x + threadIdx.x;
    if (i >= N) return;
    int m = *mode;
    int b = m ? (int)((const long long*)bt)[i] : ((const int*)bt)[i];
    batch32[i] = b;
    if (i == 0) { root_idx[0] = 0; root_idx[G] = N; }
    else {
        int bp = m ? (int)((const long long*)bt)[i - 1] : ((const int*)bt)[i - 1];
        if (b != bp) root_idx[b] = i;
    }
}

// Fused degree-count + ELL adjacency build. STANDALONE (rounds 12-14 lesson:
// co-running gemm with this atomic phase degrades the atomics more than the
// hidden gemm gains). Floor: 2M atomics x 32B write-through sectors + 1M ELL
// stores ~ 97 MB at ~930 GB/s ~= 104 us.
__global__ void ell_build(const void* __restrict__ ei, const int* __restrict__ mode,
                          int* __restrict__ deg_cnt, int* __restrict__ cnt_col,
                          int* __restrict__ ell, int E) {
    int e = blockIdx.x * blockDim.x + threadIdx.x;
    if (e >= E) return;
    int r, c;
    if (*mode) {
        const long long* p = (const long long*)ei;
        r = (int)p[e]; c = (int)p[E + e];
    } else {
        const int* p = (const int*)ei;
        r = p[e]; c = p[E + e];
    }
    if (r != c) {
        atomicAdd(&deg_cnt[r], 1);
        int slot = atomicAdd(&cnt_col[c], 1);
        if (slot < CAP) ell[c * CAP + slot] = r;
    }
}

__global__ void dis_kernel(const int* __restrict__ deg_cnt, float* __restrict__ dis, int N) {
    int i = blockIdx.x * blockDim.x + threadIdx.x;
    if (i >= N) return;
    dis[i] = rsqrtf(1.0f + (float)deg_cnt[i]);   // deg >= 1 (self loop)
}

// per-graph root contribution: rootc[g] = relu(x[root_g]) @ w2[64:128]  (fp32)
__global__ void rootc_kernel(const float* __restrict__ x, const float* __restrict__ w2hi,
                             const int* __restrict__ root_idx, float* __restrict__ rootc, int G) {
    int g = (blockIdx.x * blockDim.x + threadIdx.x) >> 6;
    int f = threadIdx.x & 63;
    if (g >= G) return;
    const float* xr = x + (long)root_idx[g] * 64;
    float acc = 0.f;
#pragma unroll
    for (int k = 0; k < 64; ++k)
        acc = fmaf(fmaxf(xr[k], 0.f), w2hi[k * 64 + f], acc);
    rootc[(long)g * 64 + f] = acc;
}

// ---------------------------------------------------------------------------
// gemm1 (round-10 proven monolith): hs[row] = bf16( dis[row] * (x[row] @ w1) )
// 64x64 tile, 256 threads, 4x4 micro-tile, single barrier, LDS inside,
// named float4 locals, __launch_bounds__(256,4). NO k-split (round-13 lesson).
__global__ __launch_bounds__(256, 4)
void gemm1_kernel(const float* __restrict__ A, const float* __restrict__ B,
                  const float* __restrict__ dis, unsigned short* __restrict__ hs, int N) {
    __shared__ float AsT[64][68];   // [k][row]
    __shared__ float Bs[64][64];    // [k][col]
    const int tid = threadIdx.x;
    const long base = (long)blockIdx.x * 64;

#pragma unroll
    for (int u = 0; u < 4; ++u) {
        int v   = tid + u * 256;
        int row = v >> 4;
        int c4  = (v & 15) * 4;
        float4 bv = *(const float4*)&B[row * 64 + c4];
        *(float4*)&Bs[row][c4] = bv;
        float4 av = make_float4(0.f, 0.f, 0.f, 0.f);
        if (base + row < N) av = *(const float4*)&A[(base + row) * 64 + c4];
        AsT[c4 + 0][row] = av.x;
        AsT[c4 + 1][row] = av.y;
        AsT[c4 + 2][row] = av.z;
        AsT[c4 + 3][row] = av.w;
    }
    __syncthreads();

    const int c0 = (tid & 15) * 4;
    const int r0 = (tid >> 4) * 4;
    float4 acc0 = make_float4(0.f, 0.f, 0.f, 0.f);
    float4 acc1 = acc0, acc2 = acc0, acc3 = acc0;

#pragma unroll 4
    for (int k = 0; k < 64; ++k) {
        float4 bv = *(const float4*)&Bs[k][c0];
        float4 av = *(const float4*)&AsT[k][r0];
        acc0.x = fmaf(av.x, bv.x, acc0.x); acc0.y = fmaf(av.x, bv.y, acc0.y);
        acc0.z = fmaf(av.x, bv.z, acc0.z); acc0.w = fmaf(av.x, bv.w, acc0.w);
        acc1.x = fmaf(av.y, bv.x, acc1.x); acc1.y = fmaf(av.y, bv.y, acc1.y);
        acc1.z = fmaf(av.y, bv.z, acc1.z); acc1.w = fmaf(av.y, bv.w, acc1.w);
        acc2.x = fmaf(av.z, bv.x, acc2.x); acc2.y = fmaf(av.z, bv.y, acc2.y);
        acc2.z = fmaf(av.z, bv.z, acc2.z); acc2.w = fmaf(av.z, bv.w, acc2.w);
        acc3.x = fmaf(av.w, bv.x, acc3.x); acc3.y = fmaf(av.w, bv.y, acc3.y);
        acc3.z = fmaf(av.w, bv.z, acc3.z); acc3.w = fmaf(av.w, bv.w, acc3.w);
    }

#define STORE_ROW(i, a)                                                       \
    {                                                                         \
        long row = base + r0 + (i);                                           \
        if (row < N) {                                                        \
            float s = dis[row];                                               \
            ushort4 o;                                                        \
            o.x = f2b(s * a.x); o.y = f2b(s * a.y);                           \
            o.z = f2b(s * a.z); o.w = f2b(s * a.w);                           \
            *(ushort4*)&hs[row * 64 + c0] = o;                                \
        }                                                                     \
    }
    STORE_ROW(0, acc0)
    STORE_ROW(1, acc1)
    STORE_ROW(2, acc2)
    STORE_ROW(3, acc3)
#undef STORE_ROW
}

// gemm2 (round-14 validated): hs[row] = bf16( dis[row]*(relu(x2b[row]) @ B + rootc[batch]) )
__global__ __launch_bounds__(256, 4)
void gemm2_kernel(const unsigned short* __restrict__ x2b, const float* __restrict__ B,
                  const float* __restrict__ addv, const int* __restrict__ batch32,
                  const float* __restrict__ dis, unsigned short* __restrict__ hs, int N) {
    __shared__ float AsT[64][68];
    __shared__ float Bs[64][64];
    const int tid = threadIdx.x;
    const long base = (long)blockIdx.x * 64;

#pragma unroll
    for (int u = 0; u < 4; ++u) {
        int v   = tid + u * 256;
        int row = v >> 4;
        int c4  = (v & 15) * 4;
        float4 bv = *(const float4*)&B[row * 64 + c4];
        *(float4*)&Bs[row][c4] = bv;
        float a0 = 0.f, a1 = 0.f, a2 = 0.f, a3 = 0.f;
        if (base + row < N) {
            ushort4 o = *(const ushort4*)&x2b[(base + row) * 64 + c4];
            a0 = blo(o.x); a1 = blo(o.y); a2 = blo(o.z); a3 = blo(o.w);
        }
        AsT[c4 + 0][row] = fmaxf(a0, 0.f);
        AsT[c4 + 1][row] = fmaxf(a1, 0.f);
        AsT[c4 + 2][row] = fmaxf(a2, 0.f);
        AsT[c4 + 3][row] = fmaxf(a3, 0.f);
    }
    __syncthreads();

    const int c0 = (tid & 15) * 4;
    const int r0 = (tid >> 4) * 4;
    float4 acc0 = make_float4(0.f, 0.f, 0.f, 0.f);
    float4 acc1 = acc0, acc2 = acc0, acc3 = acc0;

#pragma unroll 4
    for (int k = 0; k < 64; ++k) {
        float4 bv = *(const float4*)&Bs[k][c0];
        float4 av = *(const float4*)&AsT[k][r0];
        acc0.x = fmaf(av.x, bv.x, acc0.x); acc0.y = fmaf(av.x, bv.y, acc0.y);
        acc0.z = fmaf(av.x, bv.z, acc0.z); acc0.w = fmaf(av.x, bv.w, acc0.w);
        acc1.x = fmaf(av.y, bv.x, acc1.x); acc1.y = fmaf(av.y, bv.y, acc1.y);
        acc1.z = fmaf(av.y, bv.z, acc1.z); acc1.w = fmaf(av.y, bv.w, acc1.w);
        acc2.x = fmaf(av.z, bv.x, acc2.x); acc2.y = fmaf(av.z, bv.y, acc2.y);
        acc2.z = fmaf(av.z, bv.z, acc2.z); acc2.w = fmaf(av.z, bv.w, acc2.w);
        acc3.x = fmaf(av.w, bv.x, acc3.x); acc3.y = fmaf(av.w, bv.y, acc3.y);
        acc3.z = fmaf(av.w, bv.z, acc3.z); acc3.w = fmaf(av.w, bv.w, acc3.w);
    }

#define STORE_ROW(i, a)                                                       \
    {                                                                         \
        long row = base + r0 + (i);                                           \
        if (row < N) {                                                        \
            int g = batch32[row];                                             \
            float4 adv = *(const float4*)&addv[(long)g * 64 + c0];            \
            a.x += adv.x; a.y += adv.y; a.z += adv.z; a.w += adv.w;           \
            float s = dis[row];                                               \
            ushort4 o;                                                        \
            o.x = f2b(s * a.x); o.y = f2b(s * a.y);                           \
            o.z = f2b(s * a.z); o.w = f2b(s * a.w);                           \
            *(ushort4*)&hs[row * 64 + c0] = o;                                \
        }                                                                     \
    }
    STORE_ROW(0, acc0)
    STORE_ROW(1, acc1)
    STORE_ROW(2, acc2)
    STORE_ROW(3, acc3)
#undef STORE_ROW
}

// ---------------------------------------------------------------------------
// Pair-gather: one wave-load of uint (4B/lane = 256B) covers TWO edge rows
// (128B each): half = lane>>5 picks edge j+half, sl = lane&31 picks feats
// {2sl, 2sl+1}. Halves are summed at the end via shfl_xor(32). Unroll 4 ->
// 8 edges in MLP flight per iteration (2x round-10's gather).
// Returns per-lane partial (a0 = feat 2sl, a1 = feat 2sl+1), valid on ALL
// lanes after the final xor-combine.
__device__ inline void pair_gather(const unsigned* __restrict__ U,
                                   const int* __restrict__ row, int cnt,
                                   int half, int sl, float& A0, float& A1) {
    int lane = half * 32 + sl;
    int rv = (lane < cnt) ? row[lane] : 0;
    float a0 = 0.f, a1 = 0.f;
    int j = 0;
    for (; j + 8 <= cnt; j += 8) {
        int s0 = __shfl(rv, j + 0 + half, 64);
        int s1 = __shfl(rv, j + 2 + half, 64);
        int s2 = __shfl(rv, j + 4 + half, 64);
        int s3 = __shfl(rv, j + 6 + half, 64);
        unsigned u0 = U[s0 * 32 + sl];
        unsigned u1 = U[s1 * 32 + sl];
        unsigned u2 = U[s2 * 32 + sl];
        unsigned u3 = U[s3 * 32 + sl];
        a0 += blo(u0); a1 += bhi(u0);
        a0 += blo(u1); a1 += bhi(u1);
        a0 += blo(u2); a1 += bhi(u2);
        a0 += blo(u3); a1 += bhi(u3);
    }
    for (; j + 2 <= cnt; j += 2) {
        int s = __shfl(rv, j + half, 64);
        unsigned u = U[s * 32 + sl];
        a0 += blo(u); a1 += bhi(u);
    }
    if (j < cnt) {                      // odd leftover: half 0 only
        int s = __shfl(rv, j, 64);
        if (half == 0) {
            unsigned u = U[s * 32 + sl];
            a0 += blo(u); a1 += bhi(u);
        }
    }
    a0 += __shfl_xor(a0, 32, 64);
    a1 += __shfl_xor(a1, 32, 64);
    A0 = a0; A1 = a1;
}

// conv1 aggregation (prescaled hs), bf16 output:
//   x2b[node][f] = bf16( dis[node]*(Sum_e hs[r][f] + hs[node][f]) + b1[f] )
__global__ void agg1_kernel(const unsigned short* __restrict__ hs, const float* __restrict__ dis,
                            const int* __restrict__ cnt_col, const int* __restrict__ ell,
                            const float* __restrict__ bias, unsigned short* __restrict__ x2b,
                            int N) {
    int node = (blockIdx.x * blockDim.x + threadIdx.x) >> 6;
    int lane = threadIdx.x & 63;
    if (node >= N) return;
    int half = lane >> 5, sl = lane & 31;
    int cnt = min(cnt_col[node], CAP);
    const unsigned* U = (const unsigned*)hs;
    float a0, a1;
    pair_gather(U, ell + (long)node * CAP, cnt, half, sl, a0, a1);
    if (half == 0) {
        float dc = dis[node];
        unsigned sv = U[node * 32 + sl];
        float2 bv = *(const float2*)&bias[sl * 2];
        float v0 = fmaf(dc, a0 + blo(sv), bv.x);
        float v1 = fmaf(dc, a1 + bhi(sv), bv.y);
        ((unsigned*)x2b)[(long)node * 32 + sl] = pk2(v0, v1);
    }
}

// conv2 aggregation partials (4 chunks/graph, 4 waves/block):
//   s[f] = Sum_n relu(dis[n]*(Sum_e hs[r][f] + hs[n][f]) + b2[f])
__global__ __launch_bounds__(256)
void agg2_part(const unsigned short* __restrict__ hs, const float* __restrict__ dis,
               const int* __restrict__ cnt_col, const int* __restrict__ ell,
               const float* __restrict__ bias, const int* __restrict__ root_idx,
               float* __restrict__ partial) {
    __shared__ float ls[4][64];
    int g  = blockIdx.x >> 2;
    int ch = blockIdx.x & 3;
    int root = root_idx[g], nend = root_idx[g + 1];
    int len = nend - root;
    int chunk = (len + 3) >> 2;
    int start = root + ch * chunk;
    int end   = min(start + chunk, nend);
    int wid  = threadIdx.x >> 6;
    int lane = threadIdx.x & 63;
    int half = lane >> 5, sl = lane & 31;
    const unsigned* U = (const unsigned*)hs;
    float2 bv = *(const float2*)&bias[sl * 2];
    float s0 = 0.f, s1 = 0.f;
    for (int node = start + wid; node < end; node += 4) {
        int cnt = min(cnt_col[node], CAP);
        float a0, a1;
        pair_gather(U, ell + (long)node * CAP, cnt, half, sl, a0, a1);
        float dc = dis[node];
        unsigned sv = U[node * 32 + sl];
        s0 += fmaxf(fmaf(dc, a0 + blo(sv), bv.x), 0.f);
        s1 += fmaxf(fmaf(dc, a1 + bhi(sv), bv.y), 0.f);
    }
    if (half == 0) {
        ls[wid][sl * 2]     = s0;
        ls[wid][sl * 2 + 1] = s1;
    }
    __syncthreads();
    if (threadIdx.x < 64) {
        float v = ls[0][threadIdx.x] + ls[1][threadIdx.x] +
                  ls[2][threadIdx.x] + ls[3][threadIdx.x];
        partial[(long)blockIdx.x * 64 + threadIdx.x] = v;
    }
}

// final: out[g][0:64] = (Sum of 4 chunk partials)/len ; out[g][64:128] = x2b[root]
__global__ void final_reduce(const float* __restrict__ partial, const int* __restrict__ root_idx,
                             const unsigned short* __restrict__ x2b, float* __restrict__ out) {
    int g = blockIdx.x;
    int f = threadIdx.x;    // 64
    int root = root_idx[g];
    int len  = root_idx[g + 1] - root;
    const float* p = partial + (long)g * 4 * 64;
    float v = p[f] + p[64 + f] + p[128 + f] + p[192 + f];
    out[(long)g * CAT_F + f] = v / (float)len;
    out[(long)g * CAT_F + 64 + f] = blo((unsigned)x2b[(long)root * 64 + f]);
}

// ---------------------------------------------------------------------------
extern "C" void kernel_launch(void* const* d_in, const int* in_sizes, int n_in,
                              void* d_out, int out_size, void* d_ws, size_t ws_size,
                              hipStream_t stream) {
    const float* x  = (const float*)d_in[0];
    const void*  ei = d_in[1];
    const void*  bt = d_in[2];
    const float* w1 = (const float*)d_in[3];
    const float* b1 = (const float*)d_in[4];
    const float* w2 = (const float*)d_in[5];
    const float* b2 = (const float*)d_in[6];
    float* out = (float*)d_out;

    const int N = in_sizes[0] / FEAT;     // 100000
    const int E = in_sizes[1] / 2;        // 1000000
    const int G = out_size / CAT_F;       // 500

    // workspace layout
    char* p = (char*)d_ws;
    size_t off = 0;
    auto alloc = [&](size_t bytes) {
        void* q = p + off;
        off = (off + bytes + 255) & ~(size_t)255;
        return q;
    };
    int*   mode     = (int*)  alloc(sizeof(int));
    int*   batch32  = (int*)  alloc((size_t)N * sizeof(int));
    int*   deg_cnt  = (int*)  alloc((size_t)N * sizeof(int));
    float* dis      = (float*)alloc((size_t)N * sizeof(float));
    int*   cnt_col  = (int*)  alloc((size_t)N * sizeof(int));
    int*   ell      = (int*)  alloc((size_t)N * CAP * sizeof(int));
    int*   root_idx = (int*)  alloc((size_t)(G + 1) * sizeof(int));
    float* rootc    = (float*)alloc((size_t)G * FEAT * sizeof(float));
    unsigned short* hs  = (unsigned short*)alloc((size_t)N * FEAT * sizeof(unsigned short));
    unsigned short* x2b = (unsigned short*)alloc((size_t)N * FEAT * sizeof(unsigned short));
    float* partial  = (float*)alloc((size_t)G * 4 * FEAT * sizeof(float));
    (void)ws_size; (void)n_in;

    hipMemsetAsync(deg_cnt, 0, (size_t)N * sizeof(int), stream);
    hipMemsetAsync(cnt_col, 0, (size_t)N * sizeof(int), stream);

    detect_kernel<<<1, 1, 0, stream>>>((const unsigned int*)ei, mode);
    batch_prep<<<(N + 255) / 256, 256, 0, stream>>>(bt, mode, batch32, root_idx, N, G);

    // CSR(ELL) build + degrees (standalone — fusion abandoned, r12-r14), then dis
    ell_build<<<(E + 255) / 256, 256, 0, stream>>>(ei, mode, deg_cnt, cnt_col, ell, E);
    dis_kernel<<<(N + 255) / 256, 256, 0, stream>>>(deg_cnt, dis, N);

    const int gb = (N + 63) / 64;
    const int agg_blocks = (N + 3) / 4;

    // rootc (independent; needs only x + root_idx)
    rootc_kernel<<<(G + 3) / 4, 256, 0, stream>>>(x, w2 + FEAT * FEAT, root_idx, rootc, G);

    // conv1: hs = bf16(dis * (x @ w1)) ; x2b = bf16(agg(hs) + b1)
    gemm1_kernel<<<gb, 256, 0, stream>>>(x, w1, dis, hs, N);
    agg1_kernel<<<agg_blocks, 256, 0, stream>>>(hs, dis, cnt_col, ell, b1, x2b, N);

    // conv2: hs = bf16(dis * (relu(x2b) @ w2lo + rootc[batch]))
    gemm2_kernel<<<gb, 256, 0, stream>>>(x2b, w2, rootc, batch32, dis, hs, N);

    // conv2 aggregation partials (4 chunks per graph) + deterministic reduce
    agg2_part<<<G * 4, 256, 0, stream>>>(hs, dis, cnt_col, ell, b2, root_idx, partial);
    final_reduce<<<G, 64, 0, stream>>>(partial, root_idx, x2b, out);
}